// Round 4
// baseline (617.864 us; speedup 1.0000x reference)
//
#include <hip/hip_runtime.h>

// Contracter: out[z,u,k] = sum_{i,j} x1[z,u,i]*x2[z,u,j]*ww[u,k,i,j],
// ww[u,k,i,j] = sum_p weights[u,p]*w3j[p,k,i,j]. Z=50000, 64 channels, BASE=9.
//
// R1 (144us): lane=z, 36B/lane span, dword access -> TCP transaction-bound.
// R2 (178us): LDS staging -> barrier/latency-bound. Reverted.
// R3 (285us): 144B/lane span float4 -> GRANULE over-fetch: FETCH 652MB=2.8x
//             inputs (~256B fill granules vs 144B spans), HBM-bound at 2.8TB/s.
// R4: widen per-lane contiguous span to 576B (16 u per z-lane, 4 chunks of
//     4 u in registers) -> granule over-fetch ~1.1x; stores full-line.
//     Single-wave blocks (64 thr), no LDS, no barriers; coefficients stay
//     packed path-major per u -> sequential SMRD. Grid 782 z-tiles x 4
//     u-ranges = 3128 waves.

#define MUL   64
#define BASE  9
#define NPATH 11
#define NC    363   // packed coefficients per channel
#define CPAD  368

#define PATH_TABLES \
    constexpr int P1[NPATH] = {0,0,0,1,1,1,1,2,2,2,2}; \
    constexpr int P2[NPATH] = {0,1,2,0,1,1,2,0,1,2,2}; \
    constexpr int PO[NPATH] = {0,1,2,1,0,2,1,2,1,0,2}; \
    constexpr int NL[3]  = {1,3,5}; \
    constexpr int OFF[3] = {0,1,4};

// Fold per-channel path weights into packed path-major coefficient rows:
// cw[u][idx], idx enumerating (p; i in n1; j in n2; k in no).
__global__ __launch_bounds__(384) void fold_pack_kernel(
    const float* __restrict__ weights,   // (64, 11)
    const float* __restrict__ w3j,       // (11, 9, 9, 9) as (p, k, i, j)
    float*       __restrict__ cw)        // (64, CPAD)
{
    PATH_TABLES
    constexpr int SZ[NPATH] = {1,9,25,9,9,45,45,25,45,25,125}; // n1*n2*no

    int u   = blockIdx.x;
    int idx = threadIdx.x;
    if (idx >= NC) return;

    int p = 0, rem = idx;
    while (rem >= SZ[p]) { rem -= SZ[p]; ++p; }
    int n2 = NL[P2[p]], no = NL[PO[p]];
    int i  = rem / (n2 * no);
    int r  = rem - i * (n2 * no);
    int j  = r / no;
    int k  = r - j * no;
    int gi = OFF[P1[p]] + i;
    int gj = OFF[P2[p]] + j;
    int gk = OFF[PO[p]] + k;

    cw[u * CPAD + idx] = weights[u * NPATH + p] * w3j[p * 729 + gk * 81 + gi * 9 + gj];
}

__global__ __launch_bounds__(64) void tp_kernel(
    const float* __restrict__ x1,
    const float* __restrict__ x2,
    const float* __restrict__ cw,        // (64, CPAD) packed
    float*       __restrict__ out,
    int Z)
{
    PATH_TABLES

    // block = one wave; b = zt*4 + ur keeps the 4 u-ranges of a z-tile
    // adjacent in dispatch so boundary granules share L2/L3 temporally.
    int b    = blockIdx.x;
    int zt   = b >> 2;
    int ur   = b & 3;               // u-range: 16 channels
    int lane = threadIdx.x;

    int z    = zt * 64 + lane;
    bool act = (z < Z);
    int zc   = act ? z : (Z - 1);

    int ubase = ur * 16;
    const float4* a4 = (const float4*)(x1 + (size_t)zc * (MUL * BASE) + ubase * BASE);
    const float4* b4 = (const float4*)(x2 + (size_t)zc * (MUL * BASE) + ubase * BASE);
    float4*       o4 = (float4*)(out + (size_t)z  * (MUL * BASE) + ubase * BASE);

#pragma unroll
    for (int c = 0; c < 4; ++c) {          // 4 chunks x 4 u = 16 u per lane
        float4 Av[9], Bv[9];
#pragma unroll
        for (int i = 0; i < 9; ++i) { Av[i] = a4[c * 9 + i]; Bv[i] = b4[c * 9 + i]; }
        const float* X1 = (const float*)Av;    // 4 channels x 9 components
        const float* X2 = (const float*)Bv;

        float4 Ov[9];
        float* O = (float*)Ov;
#pragma unroll
        for (int k = 0; k < 36; ++k) O[k] = 0.f;

#pragma unroll
        for (int uu = 0; uu < 4; ++uu) {
            int u = ubase + c * 4 + uu;                    // blockIdx-derived: uniform
            const float* __restrict__ cr = cw + (size_t)u * CPAD;  // SMRD
            const float* xa = X1 + uu * BASE;
            const float* xb = X2 + uu * BASE;
            float*       oo = O  + uu * BASE;

            int cc = 0;   // compile-time after unroll; order matches fold_pack
#pragma unroll
            for (int p = 0; p < NPATH; ++p) {
                const int o1 = OFF[P1[p]], n1 = NL[P1[p]];
                const int o2 = OFF[P2[p]], n2 = NL[P2[p]];
                const int og = OFF[PO[p]], no = NL[PO[p]];
#pragma unroll
                for (int i = 0; i < n1; ++i) {
                    float a = xa[o1 + i];
#pragma unroll
                    for (int j = 0; j < n2; ++j) {
                        float rv = a * xb[o2 + j];
#pragma unroll
                        for (int k = 0; k < no; ++k) {
                            oo[og + k] = fmaf(cr[cc], rv, oo[og + k]);
                            ++cc;
                        }
                    }
                }
            }
        }

        if (act) {
#pragma unroll
            for (int i = 0; i < 9; ++i) o4[c * 9 + i] = Ov[i];
        }
    }
}

extern "C" void kernel_launch(void* const* d_in, const int* in_sizes, int n_in,
                              void* d_out, int out_size, void* d_ws, size_t ws_size,
                              hipStream_t stream) {
    const float* x1  = (const float*)d_in[0];
    const float* x2  = (const float*)d_in[1];
    const float* w   = (const float*)d_in[2];   // (64, 11)
    const float* w3j = (const float*)d_in[3];   // (11, 729)
    float* out = (float*)d_out;
    float* cw  = (float*)d_ws;                  // (64, CPAD) scratch

    int Z = in_sizes[0] / (MUL * BASE);

    fold_pack_kernel<<<MUL, 384, 0, stream>>>(w, w3j, cw);

    int nzt  = (Z + 63) / 64;                   // 782
    int grid = nzt * 4;                         // x 4 u-ranges of 16 u
    tp_kernel<<<grid, 64, 0, stream>>>(x1, x2, cw, out, Z);
}